// Round 16
// baseline (223.668 us; speedup 1.0000x reference)
//
#include <hip/hip_runtime.h>

// SMPL forward: B=512 batches, V=6890 verts, NB=10 shape dims, NJ=24 joints, 9 extra joints.
// Output fp32 (B, V+33, 3).
//
// Round-16 structure (4 kernel nodes, no memset):
//   transpose_kernel (27x3)  — coalesced-operand build; part-2 block 0 also
//                               zeros the jtjs atomic accumulator (memset node
//                               folded in).
//   pre_kernel     (17x24)    — jtjs via atomicAdd + linearized extra ops.
//   joints_kernel  (512x64)   — Rodrigues + chain + A + 27 extra outputs.
//   lbs_kernel     (27x128)   — NEW A-delivery (branch 7): coalesced
//                               vector-load of A into 5 VGPRs/lane +
//                               v_readlane broadcast into v_fmac. Removes the
//                               serial scalar-drain entirely (no SGPR-file
//                               bottleneck, no LDS pipe, no per-lane flat).
//
// lbs A-delivery tree: s_load/BPB4 = 52.0 << BPB1 57 < LDS-broadcast 114 <
// VPT2-stream 173 < VPT2-pin 178 < vector-flat 203. Branch 7 (this round):
// cycle model says 1200-1500 cy/batch vs s_load's ~2000 (660 issue + 1350
// drain). Math is bitwise-identical (same values, same fma order).
// Never set the 2nd __launch_bounds__ arg (spilled r2/r4). Grid-wide sync is
// catastrophic on this chip (r14: ~200 µs/barrier across 8 XCD L2s).
// Residue model (r14/r15): harness floor ~56 µs + small kernels/gaps ~60 µs,
// insensitive to small-kernel structure (120-124 across all configs).

#define BATCH 512
#define NV 6890
#define NBD 10
#define NJ 24
#define NEXTRA 9
#define NOUT (NV + NJ + NEXTRA)   // 6923
#define VBLK ((NV + 255) / 256)   // 27
#define BPB 4                     // batches per block in LBS kernel
#define PCHUNK 8                  // jtjs V-chunks
#define PCLEN ((NV + PCHUNK - 1) / PCHUNK)  // 862
#define EPN 34                    // per-(e,j) operator floats: 3 P0 + 30 PL + 1 W

__constant__ int c_par[NJ] = {-1,0,0,0,1,2,3,4,5,6,7,8,9,9,9,12,13,14,16,17,18,19,20,21};
// kinematic depth of each joint (parent of depth-k joint has depth k-1)
__constant__ int c_dep[NJ] = {0,1,1,1,2,2,2,3,3,3,4,4,4,4,4,5,5,5,6,6,7,7,8,8};

// ---------------------------------------------------------------------------
// Kernel T: one-time operand transpose, 3-way split for wave count.
// part 0: vtT (blend folded) + sdT rows 0..13
// part 1: sdT rows 14..29
// part 2: lbswT; block 0 additionally zeros jtjs (replaces the memset node).
// ---------------------------------------------------------------------------
__global__ __launch_bounds__(256) void transpose_kernel(
    const float* __restrict__ smpl_t,
    const float* __restrict__ smil_t,
    const float* __restrict__ sdirs,
    const float* __restrict__ lbsw,
    const float* __restrict__ msc,
    float* __restrict__ vtT,
    float* __restrict__ sdT,
    float* __restrict__ lbswT,
    float* __restrict__ jtjs)
{
    const int part = blockIdx.y;
    // zero the atomic accumulator (before any pre_kernel block runs — pre is
    // a later graph node, so ordering is guaranteed)
    if (part == 2 && blockIdx.x == 0) {
        for (int t = threadIdx.x; t < NJ * 33; t += 256) jtjs[t] = 0.f;
    }
    const int v = blockIdx.x * 256 + threadIdx.x;
    if (v >= NV) return;

    if (part == 0) {
        const float s = msc[0];
#pragma unroll
        for (int k = 0; k < 3; ++k)
            vtT[k * NV + v] = s * smpl_t[v * 3 + k] + (1.f - s) * smil_t[v * 3 + k];
        const float2* sd2 = (const float2*)(sdirs + (size_t)v * 30);
#pragma unroll
        for (int i = 0; i < 7; ++i) {
            float2 x = sd2[i];
            sdT[(2 * i) * NV + v]     = x.x;
            sdT[(2 * i + 1) * NV + v] = x.y;
        }
    } else if (part == 1) {
        const float2* sd2 = (const float2*)(sdirs + (size_t)v * 30);
#pragma unroll
        for (int i = 7; i < 15; ++i) {
            float2 x = sd2[i];
            sdT[(2 * i) * NV + v]     = x.x;
            sdT[(2 * i + 1) * NV + v] = x.y;
        }
    } else {
        const float4* w4 = (const float4*)(lbsw + (size_t)v * NJ);
#pragma unroll
        for (int i = 0; i < 6; ++i) {
            float4 x = w4[i];
            lbswT[(4 * i) * NV + v]     = x.x;
            lbswT[(4 * i + 1) * NV + v] = x.y;
            lbswT[(4 * i + 2) * NV + v] = x.z;
            lbswT[(4 * i + 3) * NV + v] = x.w;
        }
    }
}

// ---------------------------------------------------------------------------
// Kernel A (fused): batch-independent precompute. grid (PCHUNK+NEXTRA, NJ)
//  = (17, 24) = 408 blocks, block 256. All loads coalesced via vtT/sdT/lbswT.
// Role 1 (blockIdx.x < PCHUNK): jtjs partial over V-chunk c for joint j,
//   atomicAdd'ed into the pre-zeroed FINAL jtjs[24][33].
// Role 2 (blockIdx.x >= PCHUNK): linearized extra operators, e = x-PCHUNK:
//   u_v = jre[e,v] * lbsw[v,j];  epre[e][j] = {sum u*vt, sum u*sd, sum u}.
// ---------------------------------------------------------------------------
__global__ __launch_bounds__(256) void pre_kernel(
    const float* __restrict__ jreg,
    const float* __restrict__ jre,
    const float* __restrict__ vtT,
    const float* __restrict__ sdT,
    const float* __restrict__ lbswT,
    float* __restrict__ jtjs,
    float* __restrict__ epre)
{
    const int j = blockIdx.y;

    __shared__ float red[4][EPN];
    const int lane = threadIdx.x & 63, wv = threadIdx.x >> 6;

    if (blockIdx.x < PCHUNK) {
        // ----- role 1: jtjs partial over chunk, atomic-finalized -----
        const int c = blockIdx.x;
        const int vbeg = c * PCLEN;
        const int vend_ = (vbeg + PCLEN < NV) ? vbeg + PCLEN : NV;

        float acc[33];
#pragma unroll
        for (int i = 0; i < 33; ++i) acc[i] = 0.f;

        for (int v = vbeg + threadIdx.x; v < vend_; v += 256) {
            const float w = jreg[j * NV + v];
#pragma unroll
            for (int k = 0; k < 3; ++k) acc[k] = fmaf(w, vtT[k * NV + v], acc[k]);
#pragma unroll
            for (int i = 0; i < 30; ++i) acc[3 + i] = fmaf(w, sdT[i * NV + v], acc[3 + i]);
        }

#pragma unroll
        for (int i = 0; i < 33; ++i) {
            float x = acc[i];
            for (int off = 32; off; off >>= 1) x += __shfl_xor(x, off, 64);
            acc[i] = x;
        }
        if (lane == 0) {
#pragma unroll
            for (int i = 0; i < 33; ++i) red[wv][i] = acc[i];
        }
        __syncthreads();
        if (threadIdx.x < 33) {
            atomicAdd(&jtjs[j * 33 + threadIdx.x],
                      red[0][threadIdx.x] + red[1][threadIdx.x]
                    + red[2][threadIdx.x] + red[3][threadIdx.x]);
        }
    } else {
        // ----- role 2: extra-joint operators for extra-joint e -----
        const int e = blockIdx.x - PCHUNK;

        float acc[EPN];
#pragma unroll
        for (int i = 0; i < EPN; ++i) acc[i] = 0.f;

        for (int v = threadIdx.x; v < NV; v += 256) {
            const float u = jre[e * NV + v] * lbswT[j * NV + v];
            acc[33] += u;
#pragma unroll
            for (int k = 0; k < 3; ++k) acc[k] = fmaf(u, vtT[k * NV + v], acc[k]);
#pragma unroll
            for (int i = 0; i < 30; ++i) acc[3 + i] = fmaf(u, sdT[i * NV + v], acc[3 + i]);
        }

#pragma unroll
        for (int i = 0; i < EPN; ++i) {
            float x = acc[i];
            for (int off = 32; off; off >>= 1) x += __shfl_xor(x, off, 64);
            acc[i] = x;
        }
        if (lane == 0) {
#pragma unroll
            for (int i = 0; i < EPN; ++i) red[wv][i] = acc[i];
        }
        __syncthreads();
        if (threadIdx.x < EPN) {
            epre[(e * NJ + j) * EPN + threadIdx.x] =
                red[0][threadIdx.x] + red[1][threadIdx.x]
              + red[2][threadIdx.x] + red[3][threadIdx.x];
        }
    }
}

// ---------------------------------------------------------------------------
// Kernel B: per-batch joints — Rodrigues, kinematic chain, A matrices, AND
// the 27 extra-joint outputs. grid BATCH, block 64. Lanes 0..23 own joint j.
// (r15 version unchanged)
// ---------------------------------------------------------------------------
__global__ __launch_bounds__(64) void joints_kernel(
    const float* __restrict__ betas,
    const float* __restrict__ body_pose,
    const float* __restrict__ glob_or,
    const float* __restrict__ transl,
    const float* __restrict__ jtjs,
    const float* __restrict__ epre,
    float* __restrict__ wsA,
    float* __restrict__ out)
{
    const int b = blockIdx.x;
    const int j = threadIdx.x;

    __shared__ float sJ[NJ][3];       // J_shaped
    __shared__ float mats[NJ][12];    // [R | rel_t], then reused for corrected A
    __shared__ float chain[NJ][12];
    __shared__ float sbeta[NBD + 1];
    __shared__ float sS[NEXTRA][NJ][3];  // beta0*(P0 + betas·PL)
    __shared__ float sW[NEXTRA][NJ];

    if (threadIdx.x < NBD + 1) sbeta[threadIdx.x] = betas[b * (NBD + 1) + threadIdx.x];
    __syncthreads();

    if (j < NJ) {
        const float* jt = jtjs + j * 33;   // final values, 33 floats

        const float beta0 = sbeta[0];
        // J_shaped[b,j,k]
#pragma unroll
        for (int k = 0; k < 3; ++k) {
            float a = jt[k];
#pragma unroll
            for (int l = 0; l < NBD; ++l) a = fmaf(sbeta[1 + l], jt[3 + k * 10 + l], a);
            sJ[j][k] = a * beta0;
        }
        // Rodrigues. angle uses rvec+1e-8 per-component; axis uses raw rvec.
        float rx, ry, rz;
        if (j == 0) {
            rx = glob_or[b * 3 + 0]; ry = glob_or[b * 3 + 1]; rz = glob_or[b * 3 + 2];
        } else {
            rx = body_pose[b * 69 + (j - 1) * 3 + 0];
            ry = body_pose[b * 69 + (j - 1) * 3 + 1];
            rz = body_pose[b * 69 + (j - 1) * 3 + 2];
        }
        float ex = rx + 1e-8f, ey = ry + 1e-8f, ez = rz + 1e-8f;
        float ang = sqrtf(ex * ex + ey * ey + ez * ez);
        float inv = 1.f / ang;
        float ax = rx * inv, ay = ry * inv, az = rz * inv;
        float c = cosf(ang), s = sinf(ang), t = 1.f - c;
        // R = I + s*K + (1-c)*K^2
        mats[j][0]  = 1.f + t * (-(ay * ay + az * az));
        mats[j][1]  = -s * az + t * (ax * ay);
        mats[j][2]  =  s * ay + t * (ax * az);
        mats[j][4]  =  s * az + t * (ax * ay);
        mats[j][5]  = 1.f + t * (-(ax * ax + az * az));
        mats[j][6]  = -s * ax + t * (ay * az);
        mats[j][8]  = -s * ay + t * (ax * az);
        mats[j][9]  =  s * ax + t * (ay * az);
        mats[j][10] = 1.f + t * (-(ax * ax + ay * ay));
    }
    __syncthreads();
    if (j < NJ) {
        const int p = c_par[j];
        float t0 = sJ[j][0], t1 = sJ[j][1], t2 = sJ[j][2];
        if (p >= 0) { t0 -= sJ[p][0]; t1 -= sJ[p][1]; t2 -= sJ[p][2]; }
        mats[j][3] = t0; mats[j][7] = t1; mats[j][11] = t2;
    }
    __syncthreads();
    // chain compose, parallel over kinematic depth levels (max depth 8).
    if (j == 0) {
#pragma unroll
        for (int k = 0; k < 12; ++k) chain[0][k] = mats[0][k];
    }
    __syncthreads();
    for (int lev = 1; lev <= 8; ++lev) {
        if (j < NJ && c_dep[j] == lev) {
            const int p = c_par[j];
            float r_[12];
#pragma unroll
            for (int r = 0; r < 3; ++r) {
#pragma unroll
                for (int col = 0; col < 4; ++col) {
                    float acc = (col == 3) ? chain[p][r * 4 + 3] : 0.f;
#pragma unroll
                    for (int q = 0; q < 3; ++q) acc = fmaf(chain[p][r * 4 + q], mats[j][q * 4 + col], acc);
                    r_[r * 4 + col] = acc;
                }
            }
#pragma unroll
            for (int k = 0; k < 12; ++k) chain[j][k] = r_[k];
        }
        __syncthreads();
    }
    if (j < NJ) {
        float A[12];
#pragma unroll
        for (int k = 0; k < 12; ++k) A[k] = chain[j][k];
        const float c0 = A[3], c1 = A[7], c2 = A[11];
        const float j0 = sJ[j][0], j1 = sJ[j][1], j2 = sJ[j][2];
        A[3]  = c0 - (A[0] * j0 + A[1] * j1 + A[2]  * j2);
        A[7]  = c1 - (A[4] * j0 + A[5] * j1 + A[6]  * j2);
        A[11] = c2 - (A[8] * j0 + A[9] * j1 + A[10] * j2);
#pragma unroll
        for (int k = 0; k < 12; ++k) wsA[((size_t)b * NJ + j) * 12 + k] = A[k];
        // stash corrected A for the extra-joint sum (mats no longer needed)
#pragma unroll
        for (int k = 0; k < 12; ++k) mats[j][k] = A[k];
        // posed joints + transl
        const float tx = transl[b * 3 + 0], ty = transl[b * 3 + 1], tz = transl[b * 3 + 2];
        const size_t o = ((size_t)b * NOUT + NV + j) * 3;
        out[o + 0] = c0 + tx; out[o + 1] = c1 + ty; out[o + 2] = c2 + tz;
    }

    // ---- extra joints: per-batch contraction of the linearized operators ----
    for (int p = threadIdx.x; p < NEXTRA * NJ; p += 64) {
        const int e  = p / NJ;
        const int jj = p - e * NJ;
        const float* ep = epre + p * EPN;
#pragma unroll
        for (int cc = 0; cc < 3; ++cc) {
            float a = ep[cc];
#pragma unroll
            for (int l = 0; l < NBD; ++l) a = fmaf(sbeta[1 + l], ep[3 + cc * 10 + l], a);
            sS[e][jj][cc] = a * sbeta[0];
        }
        sW[e][jj] = ep[33];
    }
    __syncthreads();   // mats (corrected A) + sS + sW ready
    if (threadIdx.x < 3 * NEXTRA) {
        const int e = threadIdx.x / 3;
        const int k = threadIdx.x - e * 3;
        float acc = 0.f;
#pragma unroll 4
        for (int jj = 0; jj < NJ; ++jj) {
            acc = fmaf(mats[jj][k * 4 + 0], sS[e][jj][0], acc);
            acc = fmaf(mats[jj][k * 4 + 1], sS[e][jj][1], acc);
            acc = fmaf(mats[jj][k * 4 + 2], sS[e][jj][2], acc);
            acc = fmaf(mats[jj][k * 4 + 3], sW[e][jj],    acc);
        }
        out[((size_t)b * NOUT + NV + NJ) * 3 + threadIdx.x] = acc + transl[b * 3 + k];
    }
}

// ---------------------------------------------------------------------------
// Kernel C: LBS skinning — A-delivery branch 7: coalesced vector load +
// v_readlane broadcast. Per batch: lane l cooperatively loads A floats
// {l, l+64, l+128, l+192, l+256} (5 coalesced 256B loads -> 5 VGPRs); the
// T-loop broadcasts each of the 288 floats via __builtin_amdgcn_readlane
// (compile-time lane index under full unroll) directly into v_fmac.
// Removes the serial scalar-drain chain (SGPR file held only ~96 floats ->
// ~3-5 lgkmcnt drains/batch = ~1350 stall cy; measured VALUBusy 37-39%).
// New cost model: 576 VALU ops x 2cy + one overlappable vmcnt ~= 1200-1500
// cy/batch vs 2000. Math bitwise-identical (same values, same fma order).
// Wave-staggered batch order kept from r10. Tripwires: VGPR <= 64,
// WRITE_SIZE ~41.7 MB, FETCH ~11.4 MB (A is L2-resident).
// ---------------------------------------------------------------------------
__global__ __launch_bounds__(256) void lbs_kernel(
    const float* __restrict__ betas,
    const float* __restrict__ transl,
    const float* __restrict__ msc,
    const float* __restrict__ smpl_t,
    const float* __restrict__ smil_t,
    const float* __restrict__ sdirs,
    const float* __restrict__ lbsw,
    const float* __restrict__ wsA,
    float* __restrict__ out)
{
    const int rot = __builtin_amdgcn_readfirstlane((int)(threadIdx.x >> 6) + (int)blockIdx.x);

    const int v = blockIdx.x * 256 + threadIdx.x;
    const bool valid = v < NV;
    const int vc = valid ? v : NV - 1;
    const int b0 = blockIdx.y * BPB;
    const int lane = threadIdx.x & 63;
    const float s = msc[0];

    float vt[3];
#pragma unroll
    for (int k = 0; k < 3; ++k)
        vt[k] = s * smpl_t[vc * 3 + k] + (1.f - s) * smil_t[vc * 3 + k];

    float sd[30];
    {
        const float2* sd2 = (const float2*)(sdirs + (size_t)vc * 30);
#pragma unroll
        for (int i = 0; i < 15; ++i) { float2 x = sd2[i]; sd[2 * i] = x.x; sd[2 * i + 1] = x.y; }
    }
    float w[NJ];
    {
        const float4* w4 = (const float4*)(lbsw + (size_t)vc * NJ);
#pragma unroll
        for (int i = 0; i < 6; ++i) {
            float4 x = w4[i];
            w[4 * i] = x.x; w[4 * i + 1] = x.y; w[4 * i + 2] = x.z; w[4 * i + 3] = x.w;
        }
    }

#pragma unroll
    for (int bb = 0; bb < BPB; ++bb) {
        const int b = b0 + ((bb + rot) & (BPB - 1));
        const float* __restrict__ Bb = betas + b * (NBD + 1);   // uniform → s_load (11 floats)
        const float* __restrict__ Ab = wsA + (size_t)b * NJ * 12;

        // cooperative coalesced A load: lane l holds floats l, l+64, ...
        float ar0 = Ab[lane];
        float ar1 = Ab[64 + lane];
        float ar2 = Ab[128 + lane];
        float ar3 = Ab[192 + lane];
        float ar4 = (lane < 32) ? Ab[256 + lane] : 0.f;

        // v_shaped
        float vs[3];
#pragma unroll
        for (int k = 0; k < 3; ++k) {
            float a = vt[k];
#pragma unroll
            for (int l = 0; l < NBD; ++l) a = fmaf(Bb[1 + l], sd[k * 10 + l], a);
            vs[k] = a * Bb[0];
        }

        // T = sum_j w_j * A_j (3x4); A broadcast via readlane (no scalar-mem)
        float T[12];
#pragma unroll
        for (int k = 0; k < 12; ++k) T[k] = 0.f;
#pragma unroll
        for (int jj = 0; jj < NJ; ++jj) {
            const float ww = w[jj];
#pragma unroll
            for (int k = 0; k < 12; ++k) {
                const int m = jj * 12 + k;            // compile-time constant
                int ai;
                if      (m < 64)  ai = __builtin_amdgcn_readlane(__float_as_int(ar0), m);
                else if (m < 128) ai = __builtin_amdgcn_readlane(__float_as_int(ar1), m - 64);
                else if (m < 192) ai = __builtin_amdgcn_readlane(__float_as_int(ar2), m - 128);
                else if (m < 256) ai = __builtin_amdgcn_readlane(__float_as_int(ar3), m - 192);
                else              ai = __builtin_amdgcn_readlane(__float_as_int(ar4), m - 256);
                T[k] = fmaf(ww, __int_as_float(ai), T[k]);
            }
        }

        if (valid) {
            const float tx = transl[b * 3 + 0], ty = transl[b * 3 + 1], tz = transl[b * 3 + 2];
            const size_t o = ((size_t)b * NOUT + v) * 3;
            out[o + 0] = fmaf(T[0], vs[0], fmaf(T[1], vs[1], fmaf(T[2],  vs[2], T[3])))  + tx;
            out[o + 1] = fmaf(T[4], vs[0], fmaf(T[5], vs[1], fmaf(T[6],  vs[2], T[7])))  + ty;
            out[o + 2] = fmaf(T[8], vs[0], fmaf(T[9], vs[1], fmaf(T[10], vs[2], T[11]))) + tz;
        }
    }
}

// ---------------------------------------------------------------------------
extern "C" void kernel_launch(void* const* d_in, const int* in_sizes, int n_in,
                              void* d_out, int out_size, void* d_ws, size_t ws_size,
                              hipStream_t stream) {
    const float* betas     = (const float*)d_in[0];
    const float* body_pose = (const float*)d_in[1];
    const float* glob_or   = (const float*)d_in[2];
    const float* transl    = (const float*)d_in[3];
    const float* msc       = (const float*)d_in[4];
    const float* smpl_t    = (const float*)d_in[5];
    const float* smil_t    = (const float*)d_in[6];
    const float* sdirs     = (const float*)d_in[7];
    const float* jreg      = (const float*)d_in[8];
    const float* lbsw      = (const float*)d_in[9];
    const float* jre       = (const float*)d_in[10];
    // d_in[11] = parents (hard-coded in c_par)

    float* out  = (float*)d_out;
    float* ws   = (float*)d_ws;
    float* wsA   = ws;                               // BATCH*NJ*12 = 147456 floats
    float* jtjs  = wsA + (size_t)BATCH * NJ * 12;    // NJ*33 = 792 (atomic-final)
    float* epre  = jtjs + NJ * 33;                   // NEXTRA*NJ*34 = 7344
    float* vtT   = epre + NEXTRA * NJ * EPN;         // 3*NV  = 20670
    float* sdT   = vtT + 3 * NV;                     // 30*NV = 206700
    float* lbswT = sdT + 30 * NV;                    // 24*NV = 165360

    dim3 gT(VBLK, 3);
    transpose_kernel<<<gT, 256, 0, stream>>>(smpl_t, smil_t, sdirs, lbsw, msc,
                                             vtT, sdT, lbswT, jtjs);

    dim3 gA(PCHUNK + NEXTRA, NJ);
    pre_kernel<<<gA, 256, 0, stream>>>(jreg, jre, vtT, sdT, lbswT, jtjs, epre);

    joints_kernel<<<BATCH, 64, 0, stream>>>(betas, body_pose, glob_or, transl,
                                            jtjs, epre, wsA, out);

    dim3 gC(VBLK, BATCH / BPB);
    lbs_kernel<<<gC, 256, 0, stream>>>(betas, transl, msc, smpl_t, smil_t, sdirs, lbsw, wsA, out);
}

// Round 17
// 172.532 us; speedup vs baseline: 1.2964x; 1.2964x over previous
//
#include <hip/hip_runtime.h>

// SMPL forward: B=512 batches, V=6890 verts, NB=10 shape dims, NJ=24 joints, 9 extra joints.
// Output fp32 (B, V+33, 3).
//
// Round-17 = restore the measured champion (r15, 173.0 µs) after branch 7
// (readlane broadcast) closed the lbs A-delivery tree:
//   s_load/BPB4+stagger 52.0 << BPB1 57 < readlane 104 (VALU-issue-bound,
//   VALUBusy 81%) < LDS-broadcast 114 < VPT2-stream 173 < VPT2-pin 178 <
//   vector-flat 203.  All delivery pipes measured; s_load wins.
//
// Final decomposition (r14 fusion measurement + 8 config cross-checks):
//   harness floor  ~56 µs   (node-count-insensitive)
//   small kernels  ~64 µs   (transpose+pre+joints+gaps; structure-insensitive,
//                            120-124 µs residue in every healthy config)
//   lbs            52-53 µs (VALUBusy ~38%: structural SGPR-capacity drain of
//                            288 uniform floats per 660cy of FMA)
//   total         ~173 µs
//
// Structure (1 memset + 4 kernels):
//   memset(jtjs); transpose_kernel (27x3); pre_kernel (17x24, atomic jtjs +
//   linearized extra operators); joints_kernel (512x64); lbs_kernel (27x128,
//   r10-verbatim).
//
// Hard-won rules: never set the 2nd __launch_bounds__ arg (spilled r2/r4);
// no grid-wide sync on this chip (r14: ~200 µs/barrier across 8 XCD L2s);
// LDS layouts need bank arithmetic first (r11: stride-24 = 16-way conflict);
// extra joints computed via linearization, never by re-reading the 42 MB
// vert output (r6->r7).

#define BATCH 512
#define NV 6890
#define NBD 10
#define NJ 24
#define NEXTRA 9
#define NOUT (NV + NJ + NEXTRA)   // 6923
#define VBLK ((NV + 255) / 256)   // 27
#define BPB 4                     // batches per block in LBS kernel
#define PCHUNK 8                  // jtjs V-chunks
#define PCLEN ((NV + PCHUNK - 1) / PCHUNK)  // 862
#define EPN 34                    // per-(e,j) operator floats: 3 P0 + 30 PL + 1 W

__constant__ int c_par[NJ] = {-1,0,0,0,1,2,3,4,5,6,7,8,9,9,9,12,13,14,16,17,18,19,20,21};
// kinematic depth of each joint (parent of depth-k joint has depth k-1)
__constant__ int c_dep[NJ] = {0,1,1,1,2,2,2,3,3,3,4,4,4,4,4,5,5,5,6,6,7,7,8,8};

// ---------------------------------------------------------------------------
// Kernel T: one-time operand transpose, 3-way split for wave count.
// part 0: vtT (blend folded) + sdT rows 0..13
// part 1: sdT rows 14..29
// part 2: lbswT
// ---------------------------------------------------------------------------
__global__ __launch_bounds__(256) void transpose_kernel(
    const float* __restrict__ smpl_t,
    const float* __restrict__ smil_t,
    const float* __restrict__ sdirs,
    const float* __restrict__ lbsw,
    const float* __restrict__ msc,
    float* __restrict__ vtT,
    float* __restrict__ sdT,
    float* __restrict__ lbswT)
{
    const int v = blockIdx.x * 256 + threadIdx.x;
    if (v >= NV) return;
    const int part = blockIdx.y;

    if (part == 0) {
        const float s = msc[0];
#pragma unroll
        for (int k = 0; k < 3; ++k)
            vtT[k * NV + v] = s * smpl_t[v * 3 + k] + (1.f - s) * smil_t[v * 3 + k];
        const float2* sd2 = (const float2*)(sdirs + (size_t)v * 30);
#pragma unroll
        for (int i = 0; i < 7; ++i) {
            float2 x = sd2[i];
            sdT[(2 * i) * NV + v]     = x.x;
            sdT[(2 * i + 1) * NV + v] = x.y;
        }
    } else if (part == 1) {
        const float2* sd2 = (const float2*)(sdirs + (size_t)v * 30);
#pragma unroll
        for (int i = 7; i < 15; ++i) {
            float2 x = sd2[i];
            sdT[(2 * i) * NV + v]     = x.x;
            sdT[(2 * i + 1) * NV + v] = x.y;
        }
    } else {
        const float4* w4 = (const float4*)(lbsw + (size_t)v * NJ);
#pragma unroll
        for (int i = 0; i < 6; ++i) {
            float4 x = w4[i];
            lbswT[(4 * i) * NV + v]     = x.x;
            lbswT[(4 * i + 1) * NV + v] = x.y;
            lbswT[(4 * i + 2) * NV + v] = x.z;
            lbswT[(4 * i + 3) * NV + v] = x.w;
        }
    }
}

// ---------------------------------------------------------------------------
// Kernel A (fused): batch-independent precompute. grid (PCHUNK+NEXTRA, NJ)
//  = (17, 24) = 408 blocks, block 256. All loads coalesced via vtT/sdT/lbswT.
// Role 1 (blockIdx.x < PCHUNK): jtjs partial over V-chunk c for joint j,
//   atomicAdd'ed into the memset-zeroed FINAL jtjs[24][33].
// Role 2 (blockIdx.x >= PCHUNK): linearized extra operators, e = x-PCHUNK:
//   u_v = jre[e,v] * lbsw[v,j];  epre[e][j] = {sum u*vt, sum u*sd, sum u}.
// ---------------------------------------------------------------------------
__global__ __launch_bounds__(256) void pre_kernel(
    const float* __restrict__ jreg,
    const float* __restrict__ jre,
    const float* __restrict__ vtT,
    const float* __restrict__ sdT,
    const float* __restrict__ lbswT,
    float* __restrict__ jtjs,
    float* __restrict__ epre)
{
    const int j = blockIdx.y;

    __shared__ float red[4][EPN];
    const int lane = threadIdx.x & 63, wv = threadIdx.x >> 6;

    if (blockIdx.x < PCHUNK) {
        // ----- role 1: jtjs partial over chunk, atomic-finalized -----
        const int c = blockIdx.x;
        const int vbeg = c * PCLEN;
        const int vend_ = (vbeg + PCLEN < NV) ? vbeg + PCLEN : NV;

        float acc[33];
#pragma unroll
        for (int i = 0; i < 33; ++i) acc[i] = 0.f;

        for (int v = vbeg + threadIdx.x; v < vend_; v += 256) {
            const float w = jreg[j * NV + v];
#pragma unroll
            for (int k = 0; k < 3; ++k) acc[k] = fmaf(w, vtT[k * NV + v], acc[k]);
#pragma unroll
            for (int i = 0; i < 30; ++i) acc[3 + i] = fmaf(w, sdT[i * NV + v], acc[3 + i]);
        }

#pragma unroll
        for (int i = 0; i < 33; ++i) {
            float x = acc[i];
            for (int off = 32; off; off >>= 1) x += __shfl_xor(x, off, 64);
            acc[i] = x;
        }
        if (lane == 0) {
#pragma unroll
            for (int i = 0; i < 33; ++i) red[wv][i] = acc[i];
        }
        __syncthreads();
        if (threadIdx.x < 33) {
            atomicAdd(&jtjs[j * 33 + threadIdx.x],
                      red[0][threadIdx.x] + red[1][threadIdx.x]
                    + red[2][threadIdx.x] + red[3][threadIdx.x]);
        }
    } else {
        // ----- role 2: extra-joint operators for extra-joint e -----
        const int e = blockIdx.x - PCHUNK;

        float acc[EPN];
#pragma unroll
        for (int i = 0; i < EPN; ++i) acc[i] = 0.f;

        for (int v = threadIdx.x; v < NV; v += 256) {
            const float u = jre[e * NV + v] * lbswT[j * NV + v];
            acc[33] += u;
#pragma unroll
            for (int k = 0; k < 3; ++k) acc[k] = fmaf(u, vtT[k * NV + v], acc[k]);
#pragma unroll
            for (int i = 0; i < 30; ++i) acc[3 + i] = fmaf(u, sdT[i * NV + v], acc[3 + i]);
        }

#pragma unroll
        for (int i = 0; i < EPN; ++i) {
            float x = acc[i];
            for (int off = 32; off; off >>= 1) x += __shfl_xor(x, off, 64);
            acc[i] = x;
        }
        if (lane == 0) {
#pragma unroll
            for (int i = 0; i < EPN; ++i) red[wv][i] = acc[i];
        }
        __syncthreads();
        if (threadIdx.x < EPN) {
            epre[(e * NJ + j) * EPN + threadIdx.x] =
                red[0][threadIdx.x] + red[1][threadIdx.x]
              + red[2][threadIdx.x] + red[3][threadIdx.x];
        }
    }
}

// ---------------------------------------------------------------------------
// Kernel B: per-batch joints — Rodrigues, kinematic chain, A matrices, AND
// the 27 extra-joint outputs. grid BATCH, block 64. Lanes 0..23 own joint j.
// ---------------------------------------------------------------------------
__global__ __launch_bounds__(64) void joints_kernel(
    const float* __restrict__ betas,
    const float* __restrict__ body_pose,
    const float* __restrict__ glob_or,
    const float* __restrict__ transl,
    const float* __restrict__ jtjs,
    const float* __restrict__ epre,
    float* __restrict__ wsA,
    float* __restrict__ out)
{
    const int b = blockIdx.x;
    const int j = threadIdx.x;

    __shared__ float sJ[NJ][3];       // J_shaped
    __shared__ float mats[NJ][12];    // [R | rel_t], then reused for corrected A
    __shared__ float chain[NJ][12];
    __shared__ float sbeta[NBD + 1];
    __shared__ float sS[NEXTRA][NJ][3];  // beta0*(P0 + betas·PL)
    __shared__ float sW[NEXTRA][NJ];

    if (threadIdx.x < NBD + 1) sbeta[threadIdx.x] = betas[b * (NBD + 1) + threadIdx.x];
    __syncthreads();

    if (j < NJ) {
        const float* jt = jtjs + j * 33;   // final values, 33 floats

        const float beta0 = sbeta[0];
        // J_shaped[b,j,k]
#pragma unroll
        for (int k = 0; k < 3; ++k) {
            float a = jt[k];
#pragma unroll
            for (int l = 0; l < NBD; ++l) a = fmaf(sbeta[1 + l], jt[3 + k * 10 + l], a);
            sJ[j][k] = a * beta0;
        }
        // Rodrigues. angle uses rvec+1e-8 per-component; axis uses raw rvec.
        float rx, ry, rz;
        if (j == 0) {
            rx = glob_or[b * 3 + 0]; ry = glob_or[b * 3 + 1]; rz = glob_or[b * 3 + 2];
        } else {
            rx = body_pose[b * 69 + (j - 1) * 3 + 0];
            ry = body_pose[b * 69 + (j - 1) * 3 + 1];
            rz = body_pose[b * 69 + (j - 1) * 3 + 2];
        }
        float ex = rx + 1e-8f, ey = ry + 1e-8f, ez = rz + 1e-8f;
        float ang = sqrtf(ex * ex + ey * ey + ez * ez);
        float inv = 1.f / ang;
        float ax = rx * inv, ay = ry * inv, az = rz * inv;
        float c = cosf(ang), s = sinf(ang), t = 1.f - c;
        // R = I + s*K + (1-c)*K^2
        mats[j][0]  = 1.f + t * (-(ay * ay + az * az));
        mats[j][1]  = -s * az + t * (ax * ay);
        mats[j][2]  =  s * ay + t * (ax * az);
        mats[j][4]  =  s * az + t * (ax * ay);
        mats[j][5]  = 1.f + t * (-(ax * ax + az * az));
        mats[j][6]  = -s * ax + t * (ay * az);
        mats[j][8]  = -s * ay + t * (ax * az);
        mats[j][9]  =  s * ax + t * (ay * az);
        mats[j][10] = 1.f + t * (-(ax * ax + ay * ay));
    }
    __syncthreads();
    if (j < NJ) {
        const int p = c_par[j];
        float t0 = sJ[j][0], t1 = sJ[j][1], t2 = sJ[j][2];
        if (p >= 0) { t0 -= sJ[p][0]; t1 -= sJ[p][1]; t2 -= sJ[p][2]; }
        mats[j][3] = t0; mats[j][7] = t1; mats[j][11] = t2;
    }
    __syncthreads();
    // chain compose, parallel over kinematic depth levels (max depth 8).
    if (j == 0) {
#pragma unroll
        for (int k = 0; k < 12; ++k) chain[0][k] = mats[0][k];
    }
    __syncthreads();
    for (int lev = 1; lev <= 8; ++lev) {
        if (j < NJ && c_dep[j] == lev) {
            const int p = c_par[j];
            float r_[12];
#pragma unroll
            for (int r = 0; r < 3; ++r) {
#pragma unroll
                for (int col = 0; col < 4; ++col) {
                    float acc = (col == 3) ? chain[p][r * 4 + 3] : 0.f;
#pragma unroll
                    for (int q = 0; q < 3; ++q) acc = fmaf(chain[p][r * 4 + q], mats[j][q * 4 + col], acc);
                    r_[r * 4 + col] = acc;
                }
            }
#pragma unroll
            for (int k = 0; k < 12; ++k) chain[j][k] = r_[k];
        }
        __syncthreads();
    }
    if (j < NJ) {
        float A[12];
#pragma unroll
        for (int k = 0; k < 12; ++k) A[k] = chain[j][k];
        const float c0 = A[3], c1 = A[7], c2 = A[11];
        const float j0 = sJ[j][0], j1 = sJ[j][1], j2 = sJ[j][2];
        A[3]  = c0 - (A[0] * j0 + A[1] * j1 + A[2]  * j2);
        A[7]  = c1 - (A[4] * j0 + A[5] * j1 + A[6]  * j2);
        A[11] = c2 - (A[8] * j0 + A[9] * j1 + A[10] * j2);
#pragma unroll
        for (int k = 0; k < 12; ++k) wsA[((size_t)b * NJ + j) * 12 + k] = A[k];
        // stash corrected A for the extra-joint sum (mats no longer needed)
#pragma unroll
        for (int k = 0; k < 12; ++k) mats[j][k] = A[k];
        // posed joints + transl
        const float tx = transl[b * 3 + 0], ty = transl[b * 3 + 1], tz = transl[b * 3 + 2];
        const size_t o = ((size_t)b * NOUT + NV + j) * 3;
        out[o + 0] = c0 + tx; out[o + 1] = c1 + ty; out[o + 2] = c2 + tz;
    }

    // ---- extra joints: per-batch contraction of the linearized operators ----
    for (int p = threadIdx.x; p < NEXTRA * NJ; p += 64) {
        const int e  = p / NJ;
        const int jj = p - e * NJ;
        const float* ep = epre + p * EPN;
#pragma unroll
        for (int cc = 0; cc < 3; ++cc) {
            float a = ep[cc];
#pragma unroll
            for (int l = 0; l < NBD; ++l) a = fmaf(sbeta[1 + l], ep[3 + cc * 10 + l], a);
            sS[e][jj][cc] = a * sbeta[0];
        }
        sW[e][jj] = ep[33];
    }
    __syncthreads();   // mats (corrected A) + sS + sW ready
    if (threadIdx.x < 3 * NEXTRA) {
        const int e = threadIdx.x / 3;
        const int k = threadIdx.x - e * 3;
        float acc = 0.f;
#pragma unroll 4
        for (int jj = 0; jj < NJ; ++jj) {
            acc = fmaf(mats[jj][k * 4 + 0], sS[e][jj][0], acc);
            acc = fmaf(mats[jj][k * 4 + 1], sS[e][jj][1], acc);
            acc = fmaf(mats[jj][k * 4 + 2], sS[e][jj][2], acc);
            acc = fmaf(mats[jj][k * 4 + 3], sW[e][jj],    acc);
        }
        out[((size_t)b * NOUT + NV + NJ) * 3 + threadIdx.x] = acc + transl[b * 3 + k];
    }
}

// ---------------------------------------------------------------------------
// Kernel C: LBS skinning — r10 version VERBATIM (51.8-53.0 µs, VGPR 44).
// Round-0 body, BPB=4, scalar s_load A path, wave-staggered batch order.
// A-delivery tree exhausted at 7 branches; this is the winner. Do not touch.
// ---------------------------------------------------------------------------
__global__ __launch_bounds__(256) void lbs_kernel(
    const float* __restrict__ betas,
    const float* __restrict__ transl,
    const float* __restrict__ msc,
    const float* __restrict__ smpl_t,
    const float* __restrict__ smil_t,
    const float* __restrict__ sdirs,
    const float* __restrict__ lbsw,
    const float* __restrict__ wsA,
    float* __restrict__ out)
{
    const int rot = __builtin_amdgcn_readfirstlane((int)(threadIdx.x >> 6) + (int)blockIdx.x);

    const int v = blockIdx.x * 256 + threadIdx.x;
    const bool valid = v < NV;
    const int vc = valid ? v : NV - 1;
    const int b0 = blockIdx.y * BPB;
    const float s = msc[0];

    float vt[3];
#pragma unroll
    for (int k = 0; k < 3; ++k)
        vt[k] = s * smpl_t[vc * 3 + k] + (1.f - s) * smil_t[vc * 3 + k];

    float sd[30];
    {
        const float2* sd2 = (const float2*)(sdirs + (size_t)vc * 30);
#pragma unroll
        for (int i = 0; i < 15; ++i) { float2 x = sd2[i]; sd[2 * i] = x.x; sd[2 * i + 1] = x.y; }
    }
    float w[NJ];
    {
        const float4* w4 = (const float4*)(lbsw + (size_t)vc * NJ);
#pragma unroll
        for (int i = 0; i < 6; ++i) {
            float4 x = w4[i];
            w[4 * i] = x.x; w[4 * i + 1] = x.y; w[4 * i + 2] = x.z; w[4 * i + 3] = x.w;
        }
    }

#pragma unroll
    for (int bb = 0; bb < BPB; ++bb) {
        const int b = b0 + ((bb + rot) & (BPB - 1));
        const float* __restrict__ Bb = betas + b * (NBD + 1);   // uniform
        const float* __restrict__ Ab = wsA + (size_t)b * NJ * 12; // uniform

        float vs[3];
#pragma unroll
        for (int k = 0; k < 3; ++k) {
            float a = vt[k];
#pragma unroll
            for (int l = 0; l < NBD; ++l) a = fmaf(Bb[1 + l], sd[k * 10 + l], a);
            vs[k] = a * Bb[0];
        }

        float T[12];
#pragma unroll
        for (int k = 0; k < 12; ++k) T[k] = 0.f;
#pragma unroll 4
        for (int jj = 0; jj < NJ; ++jj) {
            const float ww = w[jj];
#pragma unroll
            for (int k = 0; k < 12; ++k) T[k] = fmaf(ww, Ab[jj * 12 + k], T[k]);
        }

        if (valid) {
            const float tx = transl[b * 3 + 0], ty = transl[b * 3 + 1], tz = transl[b * 3 + 2];
            const size_t o = ((size_t)b * NOUT + v) * 3;
            out[o + 0] = fmaf(T[0], vs[0], fmaf(T[1], vs[1], fmaf(T[2],  vs[2], T[3])))  + tx;
            out[o + 1] = fmaf(T[4], vs[0], fmaf(T[5], vs[1], fmaf(T[6],  vs[2], T[7])))  + ty;
            out[o + 2] = fmaf(T[8], vs[0], fmaf(T[9], vs[1], fmaf(T[10], vs[2], T[11]))) + tz;
        }
    }
}

// ---------------------------------------------------------------------------
extern "C" void kernel_launch(void* const* d_in, const int* in_sizes, int n_in,
                              void* d_out, int out_size, void* d_ws, size_t ws_size,
                              hipStream_t stream) {
    const float* betas     = (const float*)d_in[0];
    const float* body_pose = (const float*)d_in[1];
    const float* glob_or   = (const float*)d_in[2];
    const float* transl    = (const float*)d_in[3];
    const float* msc       = (const float*)d_in[4];
    const float* smpl_t    = (const float*)d_in[5];
    const float* smil_t    = (const float*)d_in[6];
    const float* sdirs     = (const float*)d_in[7];
    const float* jreg      = (const float*)d_in[8];
    const float* lbsw      = (const float*)d_in[9];
    const float* jre       = (const float*)d_in[10];
    // d_in[11] = parents (hard-coded in c_par)

    float* out  = (float*)d_out;
    float* ws   = (float*)d_ws;
    float* wsA   = ws;                               // BATCH*NJ*12 = 147456 floats
    float* jtjs  = wsA + (size_t)BATCH * NJ * 12;    // NJ*33 = 792 (atomic-final)
    float* epre  = jtjs + NJ * 33;                   // NEXTRA*NJ*34 = 7344
    float* vtT   = epre + NEXTRA * NJ * EPN;         // 3*NV  = 20670
    float* sdT   = vtT + 3 * NV;                     // 30*NV = 206700
    float* lbswT = sdT + 30 * NV;                    // 24*NV = 165360

    // zero the atomic accumulator (ws is poisoned before each call)
    hipMemsetAsync(jtjs, 0, NJ * 33 * sizeof(float), stream);

    dim3 gT(VBLK, 3);
    transpose_kernel<<<gT, 256, 0, stream>>>(smpl_t, smil_t, sdirs, lbsw, msc,
                                             vtT, sdT, lbswT);

    dim3 gA(PCHUNK + NEXTRA, NJ);
    pre_kernel<<<gA, 256, 0, stream>>>(jreg, jre, vtT, sdT, lbswT, jtjs, epre);

    joints_kernel<<<BATCH, 64, 0, stream>>>(betas, body_pose, glob_or, transl,
                                            jtjs, epre, wsA, out);

    dim3 gC(VBLK, BATCH / BPB);
    lbs_kernel<<<gC, 256, 0, stream>>>(betas, transl, msc, smpl_t, smil_t, sdirs, lbsw, wsA, out);
}